// Round 1
// baseline (106.426 us; speedup 1.0000x reference)
//
#include <hip/hip_runtime.h>
#include <hip/hip_bf16.h>
#include <math.h>

#define N 4096
#define K 64
#define TILE 128

typedef __attribute__((ext_vector_type(8))) short short8;
typedef __attribute__((ext_vector_type(4))) float floatx4;

// ws layout (floats):
// [0..4095]    sqn[i] = ||x_i||^2
// [4096]       S accumulator (sum of all x^2)
// [4097..4160] m[64] column-sum accumulators
// [4161]       counter (int)
// [4162]       c1 = -log2(e)/bw

__device__ inline unsigned bfpk(float a, float b) {
    unsigned ua = __float_as_uint(a), ub = __float_as_uint(b);
    ua = (ua + 0x7fffu + ((ua >> 16) & 1u)) >> 16;   // RNE fp32->bf16
    ub = (ub + 0x7fffu + ((ub >> 16) & 1u)) >> 16;
    return ua | (ub << 16);
}

__device__ inline uint4 pack8(float4 f0, float4 f1) {
    uint4 r;
    r.x = bfpk(f0.x, f0.y);
    r.y = bfpk(f0.z, f0.w);
    r.z = bfpk(f1.x, f1.y);
    r.w = bfpk(f1.z, f1.w);
    return r;
}

// ---------------- prep: sqn[], S, m[], then bw -> c1 (last block) -------------
__global__ __launch_bounds__(256) void prep_kernel(const float* __restrict__ X,
                                                   float* __restrict__ ws) {
    float* sqn  = ws;
    float* Sacc = ws + 4096;
    float* macc = ws + 4097;
    int*   ctr  = (int*)(ws + 4161);
    float* cons = ws + 4162;

    const int lane = threadIdx.x & 63;
    const int gw   = blockIdx.x * 4 + (threadIdx.x >> 6);  // 32 blocks * 4 waves = 128
    const int row0 = gw * 32;                              // 32 rows per wave

    float mloc = 0.f, Sloc = 0.f;
    for (int rr = 0; rr < 32; ++rr) {
        int row = row0 + rr;
        float x  = X[row * 64 + lane];   // lane = column, coalesced
        float x2 = x * x;
        mloc += x;
        Sloc += x2;
        float v = x2;
        #pragma unroll
        for (int off = 32; off > 0; off >>= 1) v += __shfl_xor(v, off, 64);
        if (lane == 0) sqn[row] = v;
    }
    #pragma unroll
    for (int off = 32; off > 0; off >>= 1) Sloc += __shfl_xor(Sloc, off, 64);
    if (lane == 0) atomicAdd(Sacc, Sloc);
    atomicAdd(&macc[lane], mloc);

    __syncthreads();
    if (threadIdx.x == 0) {
        int tkt = __hip_atomic_fetch_add(ctr, 1, __ATOMIC_ACQ_REL, __HIP_MEMORY_SCOPE_AGENT);
        if (tkt == (int)gridDim.x - 1) {
            double mm = 0.0;
            for (int d = 0; d < 64; ++d) {
                float md = __hip_atomic_load(&macc[d], __ATOMIC_RELAXED, __HIP_MEMORY_SCOPE_AGENT);
                mm += (double)md * (double)md;
            }
            double S = (double)__hip_atomic_load(Sacc, __ATOMIC_RELAXED, __HIP_MEMORY_SCOPE_AGENT);
            double sumL2 = 2.0 * (double)N * S - 2.0 * mm;
            double bw = sumL2 / ((double)N * (double)N - (double)N);
            cons[0] = (float)(-1.4426950408889634 / bw);  // -log2(e)/bw
        }
    }
}

// ---------------- main: tiled MFMA gram + fused RBF epilogue ------------------
// LDS layout: per 128-row tile, 8 chunks of 16B (8 bf16) per row.
// slot(r, c) = 8*r + (c ^ (r & 7))  -> fragment ds_read_b128 is 2-way (free).
__global__ __launch_bounds__(256) void rbf_kernel(const float* __restrict__ X,
                                                  const float* __restrict__ ws,
                                                  float* __restrict__ out) {
    __shared__ uint4 lA[1024];   // 16 KB: rows of tile-I
    __shared__ uint4 lB[1024];   // 16 KB: rows of tile-J
    __shared__ float sR[128];
    __shared__ float sC[128];

    const float* sqn = ws;
    const float c1 = ws[4162];

    const int t  = threadIdx.x;
    const int bx = blockIdx.x, by = blockIdx.y;
    const int rowBase = by * TILE, colBase = bx * TILE;

    // ---- stage fp32 -> bf16 into swizzled LDS ----
    #pragma unroll
    for (int i = 0; i < 4; ++i) {
        int slot = i * 256 + t;
        int r = slot >> 3;
        int g = slot & 7;
        int c = g ^ (r & 7);          // chunk stored at this slot
        {
            const float4* p = (const float4*)(X + (size_t)(rowBase + r) * 64 + c * 8);
            lA[slot] = pack8(p[0], p[1]);
        }
        {
            const float4* p = (const float4*)(X + (size_t)(colBase + r) * 64 + c * 8);
            lB[slot] = pack8(p[0], p[1]);
        }
    }
    if (t < 128) sR[t] = sqn[rowBase + t];
    else         sC[t - 128] = sqn[colBase + (t - 128)];
    __syncthreads();

    const int wave = t >> 6, lane = t & 63;
    const int wr = (wave >> 1) * 64;   // wave's 64x64 quadrant
    const int wc = (wave & 1) * 64;
    const int lr = lane & 15, q = lane >> 4;

    // ---- load fragments (A and B identical layout: row m/n = lane&15, k = q*8+j) ----
    short8 a[4][2], b[4][2];
    #pragma unroll
    for (int ti = 0; ti < 4; ++ti) {
        #pragma unroll
        for (int ks = 0; ks < 2; ++ks) {
            int c = ks * 4 + q;
            int r1 = wr + ti * 16 + lr;
            a[ti][ks] = *reinterpret_cast<const short8*>(&lA[8 * r1 + (c ^ (r1 & 7))]);
            int r2 = wc + ti * 16 + lr;
            b[ti][ks] = *reinterpret_cast<const short8*>(&lB[8 * r2 + (c ^ (r2 & 7))]);
        }
    }

    floatx4 acc[4][4];
    #pragma unroll
    for (int ti = 0; ti < 4; ++ti)
        #pragma unroll
        for (int tj = 0; tj < 4; ++tj)
            acc[ti][tj] = (floatx4){0.f, 0.f, 0.f, 0.f};

    #pragma unroll
    for (int ti = 0; ti < 4; ++ti)
        #pragma unroll
        for (int tj = 0; tj < 4; ++tj) {
            acc[ti][tj] = __builtin_amdgcn_mfma_f32_16x16x32_bf16(a[ti][0], b[tj][0], acc[ti][tj], 0, 0, 0);
            acc[ti][tj] = __builtin_amdgcn_mfma_f32_16x16x32_bf16(a[ti][1], b[tj][1], acc[ti][tj], 0, 0, 0);
        }

    // ---- epilogue: L2 -> t=exp(-L2/bw) -> t^4+t^2+t+sqrt(t)+sqrt(sqrt(t)) ----
    // C layout (16x16x32): col = lane&15, row = (lane>>4)*4 + reg
    #pragma unroll
    for (int ti = 0; ti < 4; ++ti) {
        int rb = wr + ti * 16 + q * 4;
        #pragma unroll
        for (int tj = 0; tj < 4; ++tj) {
            int cl  = wc + tj * 16 + lr;
            float scj = sC[cl];
            size_t col = (size_t)(colBase + cl);
            #pragma unroll
            for (int p = 0; p < 4; ++p) {
                int rl = rb + p;
                float d2 = sR[rl] + scj - 2.0f * acc[ti][tj][p];
                d2 = fmaxf(d2, 0.0f);
                float e  = __builtin_amdgcn_exp2f(d2 * c1);  // t = exp(-L2/bw)
                float e2 = e * e;
                float e4 = e2 * e2;
                float s1 = __builtin_amdgcn_sqrtf(e);
                float s2 = __builtin_amdgcn_sqrtf(s1);
                out[(size_t)(rowBase + rl) * N + col] = e4 + e2 + e + s1 + s2;
            }
        }
    }
}

extern "C" void kernel_launch(void* const* d_in, const int* in_sizes, int n_in,
                              void* d_out, int out_size, void* d_ws, size_t ws_size,
                              hipStream_t stream) {
    const float* X = (const float*)d_in[0];
    // d_in[1] = bandwidth_multipliers = 2^{-2..2}, folded analytically into epilogue
    float* out = (float*)d_out;
    float* ws  = (float*)d_ws;

    // zero S, m[64], counter  (ws floats 4096..4161)
    hipMemsetAsync(ws + 4096, 0, 66 * sizeof(float), stream);
    prep_kernel<<<32, 256, 0, stream>>>(X, ws);
    rbf_kernel<<<dim3(N / TILE, N / TILE), 256, 0, stream>>>(X, ws, out);
}

// Round 2
// 91.392 us; speedup vs baseline: 1.1645x; 1.1645x over previous
//
#include <hip/hip_runtime.h>
#include <hip/hip_bf16.h>
#include <math.h>

#define N 4096
#define TILE 128
#define PB 128   // prep blocks / partial slots

typedef __attribute__((ext_vector_type(8))) short short8;
typedef __attribute__((ext_vector_type(4))) float floatx4;

// ws layout (floats): P[b*66 + d], b<128: d<64 = column-sum partials, [64] = sum(x^2) partial

__device__ inline unsigned bfpk(float a, float b) {
    unsigned ua = __float_as_uint(a), ub = __float_as_uint(b);
    ua = (ua + 0x7fffu + ((ua >> 16) & 1u)) >> 16;   // RNE fp32->bf16
    ub = (ub + 0x7fffu + ((ub >> 16) & 1u)) >> 16;
    return ua | (ub << 16);
}

__device__ inline uint4 pack8(float4 f0, float4 f1) {
    uint4 r;
    r.x = bfpk(f0.x, f0.y);
    r.y = bfpk(f0.z, f0.w);
    r.z = bfpk(f1.x, f1.y);
    r.w = bfpk(f1.z, f1.w);
    return r;
}

// ---------- prep: per-block partial column-sums + sum(x^2). No atomics, no init needed. ----------
__global__ __launch_bounds__(256) void prep_kernel(const float* __restrict__ X,
                                                   float* __restrict__ ws) {
    __shared__ float sm[256];
    __shared__ float ssum[4];
    const int lane = threadIdx.x & 63, w = threadIdx.x >> 6;
    const int b = blockIdx.x;
    const int row0 = (b * 4 + w) * 8;              // 8 rows per wave, 32 per block
    float mloc = 0.f, Sloc = 0.f;
    #pragma unroll
    for (int rr = 0; rr < 8; ++rr) {
        float x = X[(size_t)(row0 + rr) * 64 + lane];   // lane = column, coalesced
        mloc += x; Sloc += x * x;
    }
    sm[threadIdx.x] = mloc;
    #pragma unroll
    for (int off = 1; off < 64; off <<= 1) Sloc += __shfl_xor(Sloc, off, 64);
    if (lane == 0) ssum[w] = Sloc;
    __syncthreads();
    if (threadIdx.x < 64) {
        ws[b * 66 + threadIdx.x] =
            sm[threadIdx.x] + sm[64 + threadIdx.x] + sm[128 + threadIdx.x] + sm[192 + threadIdx.x];
    } else if (threadIdx.x == 64) {
        ws[b * 66 + 64] = ssum[0] + ssum[1] + ssum[2] + ssum[3];
    }
}

// ---------------- main: tiled MFMA gram + fused RBF epilogue ------------------
// LDS: slot(r,c) = 8*r + (c ^ (r&7)); fragment ds_read_b128 lands 2-way (free).
__global__ __launch_bounds__(256, 4) void rbf_kernel(const float* __restrict__ X,
                                                     const float* __restrict__ ws,
                                                     float* __restrict__ out) {
    __shared__ uint4 lA[1024];   // 16 KB bf16 rows of tile-I
    __shared__ uint4 lB[1024];   // 16 KB bf16 rows of tile-J
    __shared__ float sR[128];
    __shared__ float sC[128];

    const int t  = threadIdx.x;
    const int rowBase = blockIdx.y * TILE, colBase = blockIdx.x * TILE;

    // ---- stage fp32 -> bf16 into swizzled LDS; fold row-norm computation in ----
    #pragma unroll
    for (int i = 0; i < 4; ++i) {
        int slot = i * 256 + t;
        int r = slot >> 3;
        int g = slot & 7;
        int c = g ^ (r & 7);
        const float4* pa = (const float4*)(X + (size_t)(rowBase + r) * 64 + c * 8);
        float4 a0 = pa[0], a1 = pa[1];
        lA[slot] = pack8(a0, a1);
        float na = a0.x*a0.x + a0.y*a0.y + a0.z*a0.z + a0.w*a0.w
                 + a1.x*a1.x + a1.y*a1.y + a1.z*a1.z + a1.w*a1.w;
        const float4* pb = (const float4*)(X + (size_t)(colBase + r) * 64 + c * 8);
        float4 b0 = pb[0], b1 = pb[1];
        lB[slot] = pack8(b0, b1);
        float nb = b0.x*b0.x + b0.y*b0.y + b0.z*b0.z + b0.w*b0.w
                 + b1.x*b1.x + b1.y*b1.y + b1.z*b1.z + b1.w*b1.w;
        #pragma unroll
        for (int off = 1; off < 8; off <<= 1) {   // reduce across the 8 chunk-lanes of row r
            na += __shfl_xor(na, off, 64);
            nb += __shfl_xor(nb, off, 64);
        }
        if (g == 0) { sR[r] = na; sC[r] = nb; }
    }

    // ---- bw from prep partials (global loads only; overlaps staging) ----
    const int lane = t & 63;
    float mv = 0.f;
    #pragma unroll 8
    for (int b = 0; b < PB; ++b) mv += ws[b * 66 + lane];
    float Sv = ws[lane * 66 + 64] + ws[(lane + 64) * 66 + 64];
    float mm = mv * mv;
    #pragma unroll
    for (int off = 1; off < 64; off <<= 1) {
        mm += __shfl_xor(mm, off, 64);
        Sv += __shfl_xor(Sv, off, 64);
    }
    float sumL2 = 2.0f * (float)N * Sv - 2.0f * mm;
    const float c1 = -1.4426950408889634f * (float)(N * N - N) / sumL2;  // -log2(e)/bw

    __syncthreads();

    const int wave = t >> 6;
    const int wr = (wave >> 1) * 64;
    const int wc = (wave & 1) * 64;
    const int lr = lane & 15, q = lane >> 4;

    // A fragments stay resident (32 VGPR); B fragments loaded per-tj (8 VGPR)
    short8 a[4][2];
    #pragma unroll
    for (int ti = 0; ti < 4; ++ti) {
        #pragma unroll
        for (int ks = 0; ks < 2; ++ks) {
            int c = ks * 4 + q;
            int r1 = wr + ti * 16 + lr;
            a[ti][ks] = *reinterpret_cast<const short8*>(&lA[8 * r1 + (c ^ (r1 & 7))]);
        }
    }

    floatx4 acc[4][4];
    #pragma unroll
    for (int ti = 0; ti < 4; ++ti)
        #pragma unroll
        for (int tj = 0; tj < 4; ++tj)
            acc[ti][tj] = (floatx4){0.f, 0.f, 0.f, 0.f};

    #pragma unroll
    for (int tj = 0; tj < 4; ++tj) {
        int r2 = wc + tj * 16 + lr;
        short8 b0 = *reinterpret_cast<const short8*>(&lB[8 * r2 + ((q    ) ^ (r2 & 7))]);
        short8 b1 = *reinterpret_cast<const short8*>(&lB[8 * r2 + ((q + 4) ^ (r2 & 7))]);
        #pragma unroll
        for (int ti = 0; ti < 4; ++ti) {
            acc[ti][tj] = __builtin_amdgcn_mfma_f32_16x16x32_bf16(a[ti][0], b0, acc[ti][tj], 0, 0, 0);
            acc[ti][tj] = __builtin_amdgcn_mfma_f32_16x16x32_bf16(a[ti][1], b1, acc[ti][tj], 0, 0, 0);
        }
    }

    // ---- epilogue: L2 -> t=exp(-L2/bw) -> t^4 + t^2 + t + t^(1/2) + t^(1/4) ----
    // C layout (16x16x32): col = lane&15, row = (lane>>4)*4 + reg
    #pragma unroll
    for (int ti = 0; ti < 4; ++ti) {
        int rb = wr + ti * 16 + q * 4;
        #pragma unroll
        for (int tj = 0; tj < 4; ++tj) {
            int cl = wc + tj * 16 + lr;
            float scj = sC[cl];
            size_t col = (size_t)(colBase + cl);
            #pragma unroll
            for (int p = 0; p < 4; ++p) {
                int rl = rb + p;
                float d2 = sR[rl] + scj - 2.0f * acc[ti][tj][p];
                d2 = fmaxf(d2, 0.0f);
                float e  = __builtin_amdgcn_exp2f(d2 * c1);
                float e2 = e * e;
                float e4 = e2 * e2;
                float s1 = __builtin_amdgcn_sqrtf(e);
                float s2 = __builtin_amdgcn_sqrtf(s1);
                out[(size_t)(rowBase + rl) * N + col] = e4 + e2 + e + s1 + s2;
            }
        }
    }
}

extern "C" void kernel_launch(void* const* d_in, const int* in_sizes, int n_in,
                              void* d_out, int out_size, void* d_ws, size_t ws_size,
                              hipStream_t stream) {
    const float* X = (const float*)d_in[0];
    // d_in[1] = bandwidth_multipliers = 2^{-2..2}, folded analytically into the epilogue
    float* out = (float*)d_out;
    float* ws  = (float*)d_ws;

    prep_kernel<<<PB, 256, 0, stream>>>(X, ws);
    rbf_kernel<<<dim3(N / TILE, N / TILE), 256, 0, stream>>>(X, ws, out);
}

// Round 3
// 85.571 us; speedup vs baseline: 1.2437x; 1.0680x over previous
//
#include <hip/hip_runtime.h>
#include <hip/hip_bf16.h>
#include <math.h>

#define N 4096
#define PB 32   // prep blocks / partial slots

typedef __attribute__((ext_vector_type(8))) short short8;
typedef __attribute__((ext_vector_type(4))) float floatx4;

// ws layout (floats): P[b*66 + d], b<32: d<64 = column-sum partials, [64] = sum(x^2) partial

__device__ inline unsigned bfpk(float a, float b) {
    unsigned ua = __float_as_uint(a), ub = __float_as_uint(b);
    ua = (ua + 0x7fffu + ((ua >> 16) & 1u)) >> 16;   // RNE fp32->bf16
    ub = (ub + 0x7fffu + ((ub >> 16) & 1u)) >> 16;
    return ua | (ub << 16);
}

__device__ inline uint4 pack8(float4 f0, float4 f1) {
    uint4 r;
    r.x = bfpk(f0.x, f0.y);
    r.y = bfpk(f0.z, f0.w);
    r.z = bfpk(f1.x, f1.y);
    r.w = bfpk(f1.z, f1.w);
    return r;
}

// ---------- prep: per-block partial column-sums + sum(x^2). No atomics, no init. ----------
__global__ __launch_bounds__(256) void prep_kernel(const float* __restrict__ X,
                                                   float* __restrict__ ws) {
    __shared__ float sm[256];
    __shared__ float ssum[4];
    const int lane = threadIdx.x & 63, w = threadIdx.x >> 6;
    const int b = blockIdx.x;
    const int row0 = b * 128 + w * 32;             // 32 rows per wave, 128 per block
    float mloc = 0.f, Sloc = 0.f;
    #pragma unroll
    for (int rr = 0; rr < 32; ++rr) {
        float x = X[(size_t)(row0 + rr) * 64 + lane];   // lane = column, coalesced
        mloc += x; Sloc += x * x;
    }
    sm[threadIdx.x] = mloc;
    #pragma unroll
    for (int off = 1; off < 64; off <<= 1) Sloc += __shfl_xor(Sloc, off, 64);
    if (lane == 0) ssum[w] = Sloc;
    __syncthreads();
    if (threadIdx.x < 64) {
        ws[b * 66 + threadIdx.x] =
            sm[threadIdx.x] + sm[64 + threadIdx.x] + sm[128 + threadIdx.x] + sm[192 + threadIdx.x];
    } else if (threadIdx.x == 64) {
        ws[b * 66 + 64] = ssum[0] + ssum[1] + ssum[2] + ssum[3];
    }
}

// ---------------- main: symmetric half-tile MFMA gram + fused RBF epilogue ----------------
// Grid: 1056 blocks. b<64: diagonal tile d=b>>1, half h=b&1 (direct writes only).
// b>=64: off-diag upper-tri pair t=(b-64)>>1, half h=(b-64)&1; writes direct (I,J)
// and float4-vectorized transposed (J,I).
// LDS: slot(r,c) = 8*r + (c ^ (r&7)); fragment ds_read_b128 lands 2-way (free).
__global__ __launch_bounds__(256) void rbf_kernel(const float* __restrict__ X,
                                                  const float* __restrict__ ws,
                                                  float* __restrict__ out) {
    __shared__ uint4 lA[512];    // 8 KB: 64 rows (I-half)
    __shared__ uint4 lB[1024];   // 16 KB: 128 rows (J-tile)
    __shared__ float sR[64];
    __shared__ float sC[128];

    const int t_ = threadIdx.x;
    const int b  = blockIdx.x;

    int I, J, h;
    if (b < 64) {
        I = J = b >> 1; h = b & 1;
    } else {
        int t = (b - 64) >> 1; h = (b - 64) & 1;
        int i = (int)((63.0f - sqrtf((float)(3969 - 8 * t))) * 0.5f);
        while (31 * (i + 1) - ((i + 1) * i) / 2 <= t) ++i;
        while (31 * i - (i * (i - 1)) / 2 > t) --i;
        int oi = 31 * i - (i * (i - 1)) / 2;
        I = i; J = i + 1 + (t - oi);
    }
    const int rowBase = I * 128 + h * 64;
    const int colBase = J * 128;
    const bool offdiag = (I != J);

    // ---- stage fp32 -> bf16 into swizzled LDS; fold row norms in ----
    #pragma unroll
    for (int i = 0; i < 4; ++i) {       // J-tile: 128 rows
        int slot = i * 256 + t_;
        int r = slot >> 3, g = slot & 7;
        int c = g ^ (r & 7);
        const float4* p = (const float4*)(X + (size_t)(colBase + r) * 64 + c * 8);
        float4 f0 = p[0], f1 = p[1];
        lB[slot] = pack8(f0, f1);
        float nb = f0.x*f0.x + f0.y*f0.y + f0.z*f0.z + f0.w*f0.w
                 + f1.x*f1.x + f1.y*f1.y + f1.z*f1.z + f1.w*f1.w;
        #pragma unroll
        for (int off = 1; off < 8; off <<= 1) nb += __shfl_xor(nb, off, 64);
        if (g == 0) sC[r] = nb;
    }
    #pragma unroll
    for (int i = 0; i < 2; ++i) {       // I-half: 64 rows
        int slot = i * 256 + t_;
        int r = slot >> 3, g = slot & 7;
        int c = g ^ (r & 7);
        const float4* p = (const float4*)(X + (size_t)(rowBase + r) * 64 + c * 8);
        float4 f0 = p[0], f1 = p[1];
        lA[slot] = pack8(f0, f1);
        float na = f0.x*f0.x + f0.y*f0.y + f0.z*f0.z + f0.w*f0.w
                 + f1.x*f1.x + f1.y*f1.y + f1.z*f1.z + f1.w*f1.w;
        #pragma unroll
        for (int off = 1; off < 8; off <<= 1) na += __shfl_xor(na, off, 64);
        if (g == 0) sR[r] = na;
    }

    // ---- bw from prep partials (overlaps staging; wave-wide, no LDS needed) ----
    const int lane = t_ & 63;
    float mv = 0.f;
    #pragma unroll 8
    for (int pb = 0; pb < PB; ++pb) mv += ws[pb * 66 + lane];
    float Sv = (lane < PB) ? ws[lane * 66 + 64] : 0.f;
    float mm = mv * mv;
    #pragma unroll
    for (int off = 1; off < 64; off <<= 1) {
        mm += __shfl_xor(mm, off, 64);
        Sv += __shfl_xor(Sv, off, 64);
    }
    float sumL2 = 2.0f * (float)N * Sv - 2.0f * mm;
    const float c1q = -1.4426950408889634f * 0.25f * (float)((size_t)N * N - N) / sumL2; // -log2e/(4*bw)

    __syncthreads();

    const int wave = t_ >> 6;
    const int lr = lane & 15, q = lane >> 4;

    // ---- fragments: wave owns rows [wave*16, wave*16+16) of the half-tile ----
    int r1 = wave * 16 + lr;
    short8 a0 = *reinterpret_cast<const short8*>(&lA[8 * r1 + ((q    ) ^ (r1 & 7))]);
    short8 a1 = *reinterpret_cast<const short8*>(&lA[8 * r1 + ((q + 4) ^ (r1 & 7))]);

    floatx4 acc[8];
    #pragma unroll
    for (int tj = 0; tj < 8; ++tj) acc[tj] = (floatx4){0.f, 0.f, 0.f, 0.f};

    #pragma unroll
    for (int tj = 0; tj < 8; ++tj) {
        int r2 = tj * 16 + lr;
        short8 b0 = *reinterpret_cast<const short8*>(&lB[8 * r2 + ((q    ) ^ (r2 & 7))]);
        short8 b1 = *reinterpret_cast<const short8*>(&lB[8 * r2 + ((q + 4) ^ (r2 & 7))]);
        acc[tj] = __builtin_amdgcn_mfma_f32_16x16x32_bf16(a0, b0, acc[tj], 0, 0, 0);
        acc[tj] = __builtin_amdgcn_mfma_f32_16x16x32_bf16(a1, b1, acc[tj], 0, 0, 0);
    }

    // ---- epilogue: u = t^(1/4) via ONE exp2; out = u^16+u^8+u^4+u^2+u ----
    // C layout (16x16x32): col = lane&15, row = (lane>>4)*4 + reg
    const int rb = wave * 16 + q * 4;
    float sr0 = sR[rb], sr1 = sR[rb + 1], sr2 = sR[rb + 2], sr3 = sR[rb + 3];
    #pragma unroll
    for (int tj = 0; tj < 8; ++tj) {
        int cl = tj * 16 + lr;
        float scj = sC[cl];
        size_t col = (size_t)(colBase + cl);
        float4 tp;
        #pragma unroll
        for (int p = 0; p < 4; ++p) {
            float srp = (p == 0) ? sr0 : (p == 1) ? sr1 : (p == 2) ? sr2 : sr3;
            float d2 = srp + scj - 2.0f * acc[tj][p];
            d2 = fmaxf(d2, 0.0f);
            float u  = __builtin_amdgcn_exp2f(d2 * c1q);   // t^(1/4)
            float s1 = u * u;        // t^(1/2)
            float e  = s1 * s1;      // t
            float e2 = e * e;        // t^2
            float e4 = e2 * e2;      // t^4
            float val = e4 + e2 + e + s1 + u;
            out[(size_t)(rowBase + rb + p) * N + col] = val;
            ((float*)&tp)[p] = val;
        }
        if (offdiag) {
            *reinterpret_cast<float4*>(&out[col * (size_t)N + (rowBase + rb)]) = tp;
        }
    }
}

extern "C" void kernel_launch(void* const* d_in, const int* in_sizes, int n_in,
                              void* d_out, int out_size, void* d_ws, size_t ws_size,
                              hipStream_t stream) {
    const float* X = (const float*)d_in[0];
    // d_in[1] = bandwidth_multipliers = 2^{-2..2}, folded analytically into the epilogue
    float* out = (float*)d_out;
    float* ws  = (float*)d_ws;

    prep_kernel<<<PB, 256, 0, stream>>>(X, ws);
    rbf_kernel<<<1056, 256, 0, stream>>>(X, ws, out);
}